// Round 2
// baseline (406.484 us; speedup 1.0000x reference)
//
#include <hip/hip_runtime.h>
#include <cstdint>

typedef __attribute__((ext_vector_type(8))) short bf16x8;
typedef __attribute__((ext_vector_type(4))) float f32x4;
typedef __attribute__((ext_vector_type(8))) unsigned short u16x8;

typedef __attribute__((address_space(1))) unsigned int gu32_t;
typedef __attribute__((address_space(3))) unsigned int lu32_t;

#define BATCH 8192
#define DIN 1024
#define DH 1024
#define KD 2048   // DIN + DH
#define ND 4096   // 4 * DH, gate-interleaved: col = 4*n + gate

__device__ __forceinline__ unsigned short f2bf(float f) {
    union { float f; unsigned int u; } v; v.f = f;
    unsigned int u = v.u;
    u += 0x7fffu + ((u >> 16) & 1u);   // RNE (finite inputs only)
    return (unsigned short)(u >> 16);
}
__device__ __forceinline__ float sigmoidf_(float x) {
    return 1.0f / (1.0f + __expf(-x));
}
__device__ __forceinline__ float tanhf_(float x) {
    float xc = fminf(fmaxf(x, -15.0f), 15.0f);
    float e2 = __expf(2.0f * xc);
    return (e2 - 1.0f) / (e2 + 1.0f);
}

// ---------------- merged convert: A | B(gate-interleaved) | bias-sum ----------------
// tasks [0, 2M): A rows (8192x2048 bf16), 8 elems/task
// tasks [2M, 3M): B rows (4096x2048 bf16, row = 4n+gate), 8 elems/task
// tasks [3M, 3M+512): bsum (4096 floats, bsum[4n+g] = b_g_i2h[n]+b_g_h2h[n]), 8/task
__global__ void __launch_bounds__(256) convert_all(
        const float* __restrict__ x, const float* __restrict__ h,
        const float* __restrict__ Wii, const float* __restrict__ Wih,
        const float* __restrict__ Wfi, const float* __restrict__ Wfh,
        const float* __restrict__ Wgi, const float* __restrict__ Wgh,
        const float* __restrict__ Woi, const float* __restrict__ Woh,
        const float* __restrict__ bii, const float* __restrict__ bih,
        const float* __restrict__ bfi, const float* __restrict__ bfh,
        const float* __restrict__ bgi, const float* __restrict__ bgh,
        const float* __restrict__ boi, const float* __restrict__ boh,
        unsigned short* __restrict__ A, unsigned short* __restrict__ B,
        float* __restrict__ bsum) {
    const int t = blockIdx.x * 256 + threadIdx.x;
    if (t < 2097152) {                                   // ---- A ----
        const int64_t off = (int64_t)t * 8;
        const int row = (int)(off >> 11);
        const int k = (int)(off & 2047);
        const float* src = (k < DIN) ? (x + (int64_t)row * DIN + k)
                                     : (h + (int64_t)row * DH + (k - DIN));
        f32x4 v0 = *(const f32x4*)src;
        f32x4 v1 = *(const f32x4*)(src + 4);
        u16x8 o;
        o[0] = f2bf(v0[0]); o[1] = f2bf(v0[1]); o[2] = f2bf(v0[2]); o[3] = f2bf(v0[3]);
        o[4] = f2bf(v1[0]); o[5] = f2bf(v1[1]); o[6] = f2bf(v1[2]); o[7] = f2bf(v1[3]);
        *(u16x8*)(A + off) = o;
    } else if (t < 3145728) {                            // ---- B ----
        const int tb = t - 2097152;
        const int64_t off = (int64_t)tb * 8;
        const int brow = (int)(off >> 11);               // 4*n + gate
        const int k = (int)(off & 2047);
        const int gate = brow & 3;
        const int n = brow >> 2;
        const float* Wi2h = (gate == 0) ? Wii : (gate == 1) ? Wfi : (gate == 2) ? Wgi : Woi;
        const float* Wh2h = (gate == 0) ? Wih : (gate == 1) ? Wfh : (gate == 2) ? Wgh : Woh;
        const float* src = (k < 1024) ? (Wi2h + (int64_t)n * 1024 + k)
                                      : (Wh2h + (int64_t)n * 1024 + (k - 1024));
        f32x4 v0 = *(const f32x4*)src;
        f32x4 v1 = *(const f32x4*)(src + 4);
        u16x8 o;
        o[0] = f2bf(v0[0]); o[1] = f2bf(v0[1]); o[2] = f2bf(v0[2]); o[3] = f2bf(v0[3]);
        o[4] = f2bf(v1[0]); o[5] = f2bf(v1[1]); o[6] = f2bf(v1[2]); o[7] = f2bf(v1[3]);
        *(u16x8*)(B + off) = o;
    } else {                                             // ---- bias sum ----
        const int b = t - 3145728;                       // [0, 512)
#pragma unroll
        for (int i = 0; i < 8; ++i) {
            const int e = b * 8 + i;                     // [0, 4096)
            const int n = e >> 2;
            const int g = e & 3;
            const float* bi = (g == 0) ? bii : (g == 1) ? bfi : (g == 2) ? bgi : boi;
            const float* bh = (g == 0) ? bih : (g == 1) ? bfh : (g == 2) ? bgh : boh;
            bsum[e] = bi[n] + bh[n];
        }
    }
}

// ---------------- fused GEMM + LSTM cell ----------------
// preact(8192 x 4096) = A(8192x2048) * B(4096x2048)^T, col = 4n+gate.
// m97 structure: 128x128 tile, BK=32, 4 waves (2x2), 4x4 16x16x32 frags/wave,
// global_load_lds width-16 staging. Epilogue: stage preacts through 32KB LDS
// (two 64-row chunks), add bias, LSTM cell, coalesced fp32 stores of h and ct.
__global__ void __launch_bounds__(256) gemm_lstm(
        const unsigned short* __restrict__ A,
        const unsigned short* __restrict__ Bw,
        const float* __restrict__ c0,
        const float* __restrict__ bsum,
        float* __restrict__ out) {
    __shared__ __align__(16) unsigned short ldsA[128 * 32];
    __shared__ __align__(16) unsigned short ldsB[128 * 32];
    __shared__ __align__(16) float preLds[64][128];      // 32KB, total 48KB -> 3 blk/CU

    const int bid = blockIdx.x;                 // 2048 blocks, %8==0 -> bijective swizzle
    const int swz = ((bid & 7) << 8) | (bid >> 3);
    const int bm = swz >> 5;                    // 64 M-blocks
    const int bn = swz & 31;                    // 32 N-blocks
    const int t = threadIdx.x;
    const int lane = t & 63;
    const int wave = t >> 6;
    const int wm = (wave >> 1) << 6;            // wave row offset (0/64)
    const int wn = (wave & 1) << 6;             // wave col offset (0/64)

    f32x4 acc[4][4];
#pragma unroll
    for (int m = 0; m < 4; ++m)
#pragma unroll
        for (int n = 0; n < 4; ++n)
            acc[m][n] = (f32x4){0.f, 0.f, 0.f, 0.f};

    // staging: tile is 128 rows x 32 bf16 (64 B/row) = 512 x 16B chunks; thread t does chunks t, t+256
    const int c0i = t;
    const int c1i = t + 256;
    const int64_t aOff0 = (int64_t)(bm * 128 + (c0i >> 2)) * KD + ((c0i & 3) << 3);
    const int64_t aOff1 = (int64_t)(bm * 128 + (c1i >> 2)) * KD + ((c1i & 3) << 3);
    const int64_t bOff0 = (int64_t)(bn * 128 + (c0i >> 2)) * KD + ((c0i & 3) << 3);
    const int64_t bOff1 = (int64_t)(bn * 128 + (c1i >> 2)) * KD + ((c1i & 3) << 3);
    unsigned short* lA0 = &ldsA[wave * 512];          // wave-uniform LDS bases (HW adds lane*16B)
    unsigned short* lA1 = &ldsA[2048 + wave * 512];
    unsigned short* lB0 = &ldsB[wave * 512];
    unsigned short* lB1 = &ldsB[2048 + wave * 512];

    const int r = lane & 15;
    const int kq = (lane >> 4) << 3;            // 8 contiguous k per lane

    for (int k0 = 0; k0 < KD; k0 += 32) {
        __syncthreads();                        // prior reads done before overwrite
        __builtin_amdgcn_global_load_lds((const gu32_t*)(A + aOff0 + k0), (lu32_t*)lA0, 16, 0, 0);
        __builtin_amdgcn_global_load_lds((const gu32_t*)(A + aOff1 + k0), (lu32_t*)lA1, 16, 0, 0);
        __builtin_amdgcn_global_load_lds((const gu32_t*)(Bw + bOff0 + k0), (lu32_t*)lB0, 16, 0, 0);
        __builtin_amdgcn_global_load_lds((const gu32_t*)(Bw + bOff1 + k0), (lu32_t*)lB1, 16, 0, 0);
        __syncthreads();                        // barrier drains vmcnt -> LDS valid

        bf16x8 af[4], bfr[4];
#pragma unroll
        for (int m = 0; m < 4; ++m)
            af[m] = *(const bf16x8*)&ldsA[(wm + m * 16 + r) * 32 + kq];
#pragma unroll
        for (int n = 0; n < 4; ++n)
            bfr[n] = *(const bf16x8*)&ldsB[(wn + n * 16 + r) * 32 + kq];
#pragma unroll
        for (int m = 0; m < 4; ++m)
#pragma unroll
            for (int n = 0; n < 4; ++n)
                acc[m][n] = __builtin_amdgcn_mfma_f32_16x16x32_bf16(af[m], bfr[n], acc[m][n], 0, 0, 0);
    }

    // -------- fused epilogue --------
    // bias: bs[j] = (i,f,g,o) bias for n = bn*32 + (t&7)*4 + j
    f32x4 bs[4];
#pragma unroll
    for (int i = 0; i < 4; ++i)
        bs[i] = *(const f32x4*)&bsum[bn * 128 + (t & 7) * 16 + i * 4];

    const int rq = (lane >> 4) << 2;            // acc row sub-offset

#pragma unroll
    for (int c = 0; c < 2; ++c) {
        __syncthreads();                        // chunk c-1 reads done / main loop done
        if (wm == c * 64) {
            // C/D layout (verified m89/m91): col = lane&15, row = (lane>>4)*4 + j
#pragma unroll
            for (int m = 0; m < 4; ++m)
#pragma unroll
                for (int n = 0; n < 4; ++n)
#pragma unroll
                    for (int j = 0; j < 4; ++j)
                        preLds[m * 16 + rq + j][wn + n * 16 + r] = acc[m][n][j];
        }
        __syncthreads();
#pragma unroll
        for (int p = 0; p < 2; ++p) {
            const int lr = p * 32 + (t >> 3);                    // [0,64)
            const int R = bm * 128 + c * 64 + lr;                // global batch row
            f32x4 pr[4];
#pragma unroll
            for (int i = 0; i < 4; ++i)
                pr[i] = *(const f32x4*)&preLds[lr][(t & 7) * 16 + i * 4];
            const int64_t eo = (int64_t)R * DH + bn * 32 + (t & 7) * 4;
            f32x4 cv = *(const f32x4*)&c0[eo];
            f32x4 hv, ctv;
#pragma unroll
            for (int j = 0; j < 4; ++j) {
                float it = sigmoidf_(pr[j][0] + bs[j][0]);
                float ft = sigmoidf_(pr[j][1] + bs[j][1]);
                float gt = tanhf_(pr[j][2] + bs[j][2]);
                float ot = sigmoidf_(pr[j][3] + bs[j][3]);
                float ct = ft * cv[j] + it * gt;
                ctv[j] = ct;
                hv[j] = ot * tanhf_(ct);
            }
            *(f32x4*)&out[eo] = hv;
            *(f32x4*)&out[(int64_t)BATCH * DH + eo] = ctv;
        }
    }
}

extern "C" void kernel_launch(void* const* d_in, const int* in_sizes, int n_in,
                              void* d_out, int out_size, void* d_ws, size_t ws_size,
                              hipStream_t stream) {
    const float* x   = (const float*)d_in[0];
    const float* h0  = (const float*)d_in[1];
    const float* c0  = (const float*)d_in[2];
    const float* Wii = (const float*)d_in[3];
    const float* bii = (const float*)d_in[4];
    const float* Wih = (const float*)d_in[5];
    const float* bih = (const float*)d_in[6];
    const float* Wfi = (const float*)d_in[7];
    const float* bfi = (const float*)d_in[8];
    const float* Wfh = (const float*)d_in[9];
    const float* bfh = (const float*)d_in[10];
    const float* Wgi = (const float*)d_in[11];
    const float* bgi = (const float*)d_in[12];
    const float* Wgh = (const float*)d_in[13];
    const float* bgh = (const float*)d_in[14];
    const float* Woi = (const float*)d_in[15];
    const float* boi = (const float*)d_in[16];
    const float* Woh = (const float*)d_in[17];
    const float* boh = (const float*)d_in[18];

    // ws layout: A bf16 32MB | B bf16 16MB | bsum 16KB
    unsigned short* A  = (unsigned short*)d_ws;
    unsigned short* Bw = A + (size_t)BATCH * KD;
    float* bsum = (float*)(Bw + (size_t)ND * KD);
    float* out = (float*)d_out;

    convert_all<<<12290, 256, 0, stream>>>(x, h0,
        Wii, Wih, Wfi, Wfh, Wgi, Wgh, Woi, Woh,
        bii, bih, bfi, bfh, bgi, bgh, boi, boh,
        A, Bw, bsum);
    gemm_lstm<<<2048, 256, 0, stream>>>(A, Bw, c0, bsum, out);
}

// Round 3
// 334.151 us; speedup vs baseline: 1.2165x; 1.2165x over previous
//
#include <hip/hip_runtime.h>
#include <cstdint>

typedef __attribute__((ext_vector_type(8))) short bf16x8;
typedef __attribute__((ext_vector_type(4))) float f32x4;
typedef __attribute__((ext_vector_type(8))) unsigned short u16x8;

typedef __attribute__((address_space(1))) unsigned int gu32_t;
typedef __attribute__((address_space(3))) unsigned int lu32_t;

#define BATCH 8192
#define DIN 1024
#define DH 1024
#define KD 2048   // DIN + DH
#define ND 4096   // 4 * DH, gate-interleaved: col = 4*n + gate

__device__ __forceinline__ unsigned short f2bf(float f) {
    union { float f; unsigned int u; } v; v.f = f;
    unsigned int u = v.u;
    u += 0x7fffu + ((u >> 16) & 1u);   // RNE (finite inputs only)
    return (unsigned short)(u >> 16);
}
__device__ __forceinline__ float sigmoidf_(float x) {
    return 1.0f / (1.0f + __expf(-x));
}
__device__ __forceinline__ float tanhf_(float x) {
    float xc = fminf(fmaxf(x, -15.0f), 15.0f);
    float e2 = __expf(2.0f * xc);
    return (e2 - 1.0f) / (e2 + 1.0f);
}
// LDS byte-offset swizzle within a 64B (BK=32 bf16) row: bits 4-5 XORed by row bits.
// Gives balanced 8-access/bank for the 16-row x 4-slot fragment read pattern.
__device__ __forceinline__ int fswz(int r) {
    return ((r & 3) << 4) ^ ((r & 4) << 3);
}

// ---------------- merged convert: A | B(gate-interleaved) | bias-sum ----------------
__global__ void __launch_bounds__(256) convert_all(
        const float* __restrict__ x, const float* __restrict__ h,
        const float* __restrict__ Wii, const float* __restrict__ Wih,
        const float* __restrict__ Wfi, const float* __restrict__ Wfh,
        const float* __restrict__ Wgi, const float* __restrict__ Wgh,
        const float* __restrict__ Woi, const float* __restrict__ Woh,
        const float* __restrict__ bii, const float* __restrict__ bih,
        const float* __restrict__ bfi, const float* __restrict__ bfh,
        const float* __restrict__ bgi, const float* __restrict__ bgh,
        const float* __restrict__ boi, const float* __restrict__ boh,
        unsigned short* __restrict__ A, unsigned short* __restrict__ B,
        float* __restrict__ bsum) {
    const int t = blockIdx.x * 256 + threadIdx.x;
    if (t < 2097152) {                                   // ---- A ----
        const int64_t off = (int64_t)t * 8;
        const int row = (int)(off >> 11);
        const int k = (int)(off & 2047);
        const float* src = (k < DIN) ? (x + (int64_t)row * DIN + k)
                                     : (h + (int64_t)row * DH + (k - DIN));
        f32x4 v0 = *(const f32x4*)src;
        f32x4 v1 = *(const f32x4*)(src + 4);
        u16x8 o;
        o[0] = f2bf(v0[0]); o[1] = f2bf(v0[1]); o[2] = f2bf(v0[2]); o[3] = f2bf(v0[3]);
        o[4] = f2bf(v1[0]); o[5] = f2bf(v1[1]); o[6] = f2bf(v1[2]); o[7] = f2bf(v1[3]);
        *(u16x8*)(A + off) = o;
    } else if (t < 3145728) {                            // ---- B ----
        const int tb = t - 2097152;
        const int64_t off = (int64_t)tb * 8;
        const int brow = (int)(off >> 11);               // 4*n + gate
        const int k = (int)(off & 2047);
        const int gate = brow & 3;
        const int n = brow >> 2;
        const float* Wi2h = (gate == 0) ? Wii : (gate == 1) ? Wfi : (gate == 2) ? Wgi : Woi;
        const float* Wh2h = (gate == 0) ? Wih : (gate == 1) ? Wfh : (gate == 2) ? Wgh : Woh;
        const float* src = (k < 1024) ? (Wi2h + (int64_t)n * 1024 + k)
                                      : (Wh2h + (int64_t)n * 1024 + (k - 1024));
        f32x4 v0 = *(const f32x4*)src;
        f32x4 v1 = *(const f32x4*)(src + 4);
        u16x8 o;
        o[0] = f2bf(v0[0]); o[1] = f2bf(v0[1]); o[2] = f2bf(v0[2]); o[3] = f2bf(v0[3]);
        o[4] = f2bf(v1[0]); o[5] = f2bf(v1[1]); o[6] = f2bf(v1[2]); o[7] = f2bf(v1[3]);
        *(u16x8*)(B + off) = o;
    } else {                                             // ---- bias sum ----
        const int b = t - 3145728;                       // [0, 512)
#pragma unroll
        for (int i = 0; i < 8; ++i) {
            const int e = b * 8 + i;                     // [0, 4096)
            const int n = e >> 2;
            const int g = e & 3;
            const float* bi = (g == 0) ? bii : (g == 1) ? bfi : (g == 2) ? bgi : boi;
            const float* bh = (g == 0) ? bih : (g == 1) ? bfh : (g == 2) ? bgh : boh;
            bsum[e] = bi[n] + bh[n];
        }
    }
}

// ---------------- deep-pipelined 256x256 GEMM + fused LSTM cell ----------------
// preact = A(8192x2048) * B(4096x2048)^T, cols gate-interleaved (4n+g).
// BK=32, 4 LDS buffers (128KB, 1 block/CU), 8 waves (2M x 4N), counted vmcnt(8),
// one barrier per K-step, XOR-swizzled LDS, setprio around MFMA cluster.
// Epilogue fused: acc -> swizzled LDS fp32 -> bias + cell -> coalesced h/ct stores.
__global__ void __launch_bounds__(512, 2) gemm_lstm(
        const unsigned short* __restrict__ A,
        const unsigned short* __restrict__ Bw,
        const float* __restrict__ c0p,
        const float* __restrict__ bsum,
        float* __restrict__ outp) {
    __shared__ __align__(16) unsigned short lds[4][16384];   // buf: A [0,8192) | B [8192,16384)

    const int bid = blockIdx.x;                 // 512 blocks, %8==0 -> bijective XCD swizzle
    const int swz = ((bid & 7) << 6) | (bid >> 3);
    const int bm = swz & 31;                    // 32 M-blocks (consecutive swz share bn -> B reuse in XCD L2)
    const int bn = swz >> 5;                    // 16 N-blocks
    const int t = threadIdx.x;
    const int lane = t & 63;
    const int wave = t >> 6;
    const int wm = wave >> 2;                   // 0-1 (row offset wm*128)
    const int wn = wave & 3;                    // 0-3 (col offset wn*64)

    f32x4 acc[8][4];
#pragma unroll
    for (int m = 0; m < 8; ++m)
#pragma unroll
        for (int n = 0; n < 4; ++n)
            acc[m][n] = (f32x4){0.f, 0.f, 0.f, 0.f};

    // ---- staging geometry: per half-panel (128 rows x 32 k) 512 chunks of 16B ----
    // chunk c=t -> row=t>>2, 16B-slot (t&3); source k-byte = slot^fswz(row) (inverse swizzle)
    const int crow = t >> 2;                                   // 0..127
    const int kb = ((t & 3) << 4) ^ fswz(crow & 7);            // byte offset in 64B row
    const unsigned short* aS0 = A  + (size_t)(bm * 256 + crow) * KD + (kb >> 1);
    const unsigned short* aS1 = aS0 + (size_t)128 * KD;
    const unsigned short* bS0 = Bw + (size_t)(bn * 256 + crow) * KD + (kb >> 1);
    const unsigned short* bS1 = bS0 + (size_t)128 * KD;
    const int ldsDst = wave * 512;                             // wave-uniform base (elems); HW adds lane*16B

    // ---- ds-read geometry (swizzled) ----
    const int r15 = lane & 15;
    const int rdk = ((((lane >> 4) << 4) ^ fswz(r15 & 7)) >> 1);  // elem offset in row
    const int aoff = r15 * 32 + rdk;
    const int aRowBase = (wm * 128) * 32;
    const int bRowBase = 8192 + (wn * 64) * 32;

    // ---- prologue: stage tiles 0,1,2 into bufs 0,1,2 ----
#pragma unroll
    for (int pt = 0; pt < 3; ++pt) {
        unsigned short* dA = &lds[pt][ldsDst];
        unsigned short* dB = &lds[pt][8192 + ldsDst];
        __builtin_amdgcn_global_load_lds((const gu32_t*)(aS0 + pt * 32), (lu32_t*)dA, 16, 0, 0);
        __builtin_amdgcn_global_load_lds((const gu32_t*)(aS1 + pt * 32), (lu32_t*)(dA + 4096), 16, 0, 0);
        __builtin_amdgcn_global_load_lds((const gu32_t*)(bS0 + pt * 32), (lu32_t*)dB, 16, 0, 0);
        __builtin_amdgcn_global_load_lds((const gu32_t*)(bS1 + pt * 32), (lu32_t*)(dB + 4096), 16, 0, 0);
    }
    asm volatile("s_waitcnt vmcnt(8)" ::: "memory");   // tile 0 resident; tiles 1,2 in flight
    __builtin_amdgcn_sched_barrier(0);
    __builtin_amdgcn_s_barrier();
    __builtin_amdgcn_sched_barrier(0);

    // ---- main loop: 64 K-tiles; stage t+3 (buffer 2 tiles stale), vmcnt(8) keeps 2 tiles in flight ----
    for (int tt = 0; tt < 16; ++tt) {
#pragma unroll
        for (int q = 0; q < 4; ++q) {
            const int t64 = tt * 4 + q;
            if (t64 < 61) {
                const int b3 = (q + 3) & 3;
                unsigned short* dA = &lds[b3][ldsDst];
                unsigned short* dB = &lds[b3][8192 + ldsDst];
                const size_t ko = (size_t)(t64 + 3) * 32;
                __builtin_amdgcn_global_load_lds((const gu32_t*)(aS0 + ko), (lu32_t*)dA, 16, 0, 0);
                __builtin_amdgcn_global_load_lds((const gu32_t*)(aS1 + ko), (lu32_t*)(dA + 4096), 16, 0, 0);
                __builtin_amdgcn_global_load_lds((const gu32_t*)(bS0 + ko), (lu32_t*)dB, 16, 0, 0);
                __builtin_amdgcn_global_load_lds((const gu32_t*)(bS1 + ko), (lu32_t*)(dB + 4096), 16, 0, 0);
            }
            const unsigned short* aB = &lds[q][aRowBase + aoff];
            const unsigned short* bB = &lds[q][bRowBase + aoff];
            bf16x8 af[8], bf4[4];
#pragma unroll
            for (int m = 0; m < 8; ++m) af[m] = *(const bf16x8*)(aB + m * 512);
#pragma unroll
            for (int n = 0; n < 4; ++n) bf4[n] = *(const bf16x8*)(bB + n * 512);
            __builtin_amdgcn_s_setprio(1);
#pragma unroll
            for (int m = 0; m < 8; ++m)
#pragma unroll
                for (int n = 0; n < 4; ++n)
                    acc[m][n] = __builtin_amdgcn_mfma_f32_16x16x32_bf16(af[m], bf4[n], acc[m][n], 0, 0, 0);
            __builtin_amdgcn_s_setprio(0);
            if (t64 < 61)       asm volatile("s_waitcnt vmcnt(8)" ::: "memory");
            else if (t64 == 61) asm volatile("s_waitcnt vmcnt(4)" ::: "memory");
            else if (t64 == 62) asm volatile("s_waitcnt vmcnt(0)" ::: "memory");
            if (t64 < 63) {
                __builtin_amdgcn_sched_barrier(0);
                __builtin_amdgcn_s_barrier();
                __builtin_amdgcn_sched_barrier(0);
            }
        }
    }

    // ---- fused epilogue: 4 chunks of 64 rows x 256 cols via swizzled fp32 LDS re-stage ----
    float* pre = (float*)&lds[0][0];            // 64KB = [64][256] f32 (bufs 0-1, all retired)
    const int lr = t >> 3;                      // 0..63
    const int cg = t & 7;                       // 32-col group
    const int rswz = (lr & 7) << 2;
#pragma unroll
    for (int c = 0; c < 4; ++c) {
        __syncthreads();
        if (wm == (c >> 1)) {
#pragma unroll
            for (int mm = 0; mm < 4; ++mm) {
                const int m = (c & 1) * 4 + mm;
#pragma unroll
                for (int n = 0; n < 4; ++n) {
                    const int col = wn * 64 + n * 16 + r15;
#pragma unroll
                    for (int j = 0; j < 4; ++j) {
                        const int rw = mm * 16 + ((lane >> 4) << 2) + j;  // C/D: row=(lane>>4)*4+j
                        pre[rw * 256 + (col ^ ((rw & 7) << 2))] = acc[m][n][j];
                    }
                }
            }
        }
        __syncthreads();
        const int R = bm * 256 + c * 64 + lr;
        const int64_t eo = (int64_t)R * DH + bn * 64 + cg * 8;
        f32x4 cp0 = *(const f32x4*)&c0p[eo];
        f32x4 cp1 = *(const f32x4*)&c0p[eo + 4];
        float hbuf[8], cbuf[8];
#pragma unroll
        for (int g8 = 0; g8 < 8; ++g8) {
            const int colf = cg * 32 + g8 * 4;
            f32x4 pr = *(const f32x4*)&pre[lr * 256 + (colf ^ rswz)];
            f32x4 bs = *(const f32x4*)&bsum[bn * 256 + colf];
            float it = sigmoidf_(pr[0] + bs[0]);
            float ft = sigmoidf_(pr[1] + bs[1]);
            float gt = tanhf_(pr[2] + bs[2]);
            float ot = sigmoidf_(pr[3] + bs[3]);
            float cprev = (g8 < 4) ? cp0[g8 & 3] : cp1[g8 & 3];
            float ct = ft * cprev + it * gt;
            cbuf[g8] = ct;
            hbuf[g8] = ot * tanhf_(ct);
        }
        f32x4 h0v = {hbuf[0], hbuf[1], hbuf[2], hbuf[3]};
        f32x4 h1v = {hbuf[4], hbuf[5], hbuf[6], hbuf[7]};
        f32x4 c0v = {cbuf[0], cbuf[1], cbuf[2], cbuf[3]};
        f32x4 c1v = {cbuf[4], cbuf[5], cbuf[6], cbuf[7]};
        *(f32x4*)&outp[eo] = h0v;
        *(f32x4*)&outp[eo + 4] = h1v;
        *(f32x4*)&outp[(int64_t)BATCH * DH + eo] = c0v;
        *(f32x4*)&outp[(int64_t)BATCH * DH + eo + 4] = c1v;
    }
}

extern "C" void kernel_launch(void* const* d_in, const int* in_sizes, int n_in,
                              void* d_out, int out_size, void* d_ws, size_t ws_size,
                              hipStream_t stream) {
    const float* x   = (const float*)d_in[0];
    const float* h0  = (const float*)d_in[1];
    const float* c0  = (const float*)d_in[2];
    const float* Wii = (const float*)d_in[3];
    const float* bii = (const float*)d_in[4];
    const float* Wih = (const float*)d_in[5];
    const float* bih = (const float*)d_in[6];
    const float* Wfi = (const float*)d_in[7];
    const float* bfi = (const float*)d_in[8];
    const float* Wfh = (const float*)d_in[9];
    const float* bfh = (const float*)d_in[10];
    const float* Wgi = (const float*)d_in[11];
    const float* bgi = (const float*)d_in[12];
    const float* Wgh = (const float*)d_in[13];
    const float* bgh = (const float*)d_in[14];
    const float* Woi = (const float*)d_in[15];
    const float* boi = (const float*)d_in[16];
    const float* Woh = (const float*)d_in[17];
    const float* boh = (const float*)d_in[18];

    // ws layout: A bf16 32MB | B bf16 16MB | bsum 16KB
    unsigned short* A  = (unsigned short*)d_ws;
    unsigned short* Bw = A + (size_t)BATCH * KD;
    float* bsum = (float*)(Bw + (size_t)ND * KD);
    float* out = (float*)d_out;

    convert_all<<<12290, 256, 0, stream>>>(x, h0,
        Wii, Wih, Wfi, Wfh, Wgi, Wgh, Woi, Woh,
        bii, bih, bfi, bfh, bgi, bgh, boi, boh,
        A, Bw, bsum);
    gemm_lstm<<<512, 512, 0, stream>>>(A, Bw, c0, bsum, out);
}

// Round 6
// 327.704 us; speedup vs baseline: 1.2404x; 1.0197x over previous
//
#include <hip/hip_runtime.h>
#include <cstdint>

typedef __attribute__((ext_vector_type(8))) short bf16x8;
typedef __attribute__((ext_vector_type(4))) float f32x4;
typedef __attribute__((ext_vector_type(8))) unsigned short u16x8;

typedef __attribute__((address_space(1))) unsigned int gu32_t;
typedef __attribute__((address_space(3))) unsigned int lu32_t;

#define BATCH 8192
#define DIN 1024
#define DH 1024
#define KD 2048   // DIN + DH
#define ND 4096   // 4 * DH, gate-interleaved: col = 4*n + gate

__device__ __forceinline__ unsigned short f2bf(float f) {
    union { float f; unsigned int u; } v; v.f = f;
    unsigned int u = v.u;
    u += 0x7fffu + ((u >> 16) & 1u);   // RNE (finite inputs only)
    return (unsigned short)(u >> 16);
}
__device__ __forceinline__ float sigmoidf_(float x) {
    return 1.0f / (1.0f + __expf(-x));
}
__device__ __forceinline__ float tanhf_(float x) {
    float xc = fminf(fmaxf(x, -15.0f), 15.0f);
    float e2 = __expf(2.0f * xc);
    return (e2 - 1.0f) / (e2 + 1.0f);
}

// ---------------- merged convert: A | B(gate-interleaved) | bias-sum ----------------
__global__ void __launch_bounds__(256) convert_all(
        const float* __restrict__ x, const float* __restrict__ h,
        const float* __restrict__ Wii, const float* __restrict__ Wih,
        const float* __restrict__ Wfi, const float* __restrict__ Wfh,
        const float* __restrict__ Wgi, const float* __restrict__ Wgh,
        const float* __restrict__ Woi, const float* __restrict__ Woh,
        const float* __restrict__ bii, const float* __restrict__ bih,
        const float* __restrict__ bfi, const float* __restrict__ bfh,
        const float* __restrict__ bgi, const float* __restrict__ bgh,
        const float* __restrict__ boi, const float* __restrict__ boh,
        unsigned short* __restrict__ A, unsigned short* __restrict__ B,
        float* __restrict__ bsum) {
    const int t = blockIdx.x * 256 + threadIdx.x;
    if (t < 2097152) {                                   // ---- A ----
        const int64_t off = (int64_t)t * 8;
        const int row = (int)(off >> 11);
        const int k = (int)(off & 2047);
        const float* src = (k < DIN) ? (x + (int64_t)row * DIN + k)
                                     : (h + (int64_t)row * DH + (k - DIN));
        f32x4 v0 = *(const f32x4*)src;
        f32x4 v1 = *(const f32x4*)(src + 4);
        u16x8 o;
        o[0] = f2bf(v0[0]); o[1] = f2bf(v0[1]); o[2] = f2bf(v0[2]); o[3] = f2bf(v0[3]);
        o[4] = f2bf(v1[0]); o[5] = f2bf(v1[1]); o[6] = f2bf(v1[2]); o[7] = f2bf(v1[3]);
        *(u16x8*)(A + off) = o;
    } else if (t < 3145728) {                            // ---- B ----
        const int tb = t - 2097152;
        const int64_t off = (int64_t)tb * 8;
        const int brow = (int)(off >> 11);               // 4*n + gate
        const int k = (int)(off & 2047);
        const int gate = brow & 3;
        const int n = brow >> 2;
        const float* Wi2h = (gate == 0) ? Wii : (gate == 1) ? Wfi : (gate == 2) ? Wgi : Woi;
        const float* Wh2h = (gate == 0) ? Wih : (gate == 1) ? Wfh : (gate == 2) ? Wgh : Woh;
        const float* src = (k < 1024) ? (Wi2h + (int64_t)n * 1024 + k)
                                      : (Wh2h + (int64_t)n * 1024 + (k - 1024));
        f32x4 v0 = *(const f32x4*)src;
        f32x4 v1 = *(const f32x4*)(src + 4);
        u16x8 o;
        o[0] = f2bf(v0[0]); o[1] = f2bf(v0[1]); o[2] = f2bf(v0[2]); o[3] = f2bf(v0[3]);
        o[4] = f2bf(v1[0]); o[5] = f2bf(v1[1]); o[6] = f2bf(v1[2]); o[7] = f2bf(v1[3]);
        *(u16x8*)(B + off) = o;
    } else {                                             // ---- bias sum ----
        const int b = t - 3145728;                       // [0, 512)
#pragma unroll
        for (int i = 0; i < 8; ++i) {
            const int e = b * 8 + i;                     // [0, 4096)
            const int n = e >> 2;
            const int g = e & 3;
            const float* bi = (g == 0) ? bii : (g == 1) ? bfi : (g == 2) ? bgi : boi;
            const float* bh = (g == 0) ? bih : (g == 1) ? bfh : (g == 2) ? bgh : boh;
            bsum[e] = bi[n] + bh[n];
        }
    }
}

// ---------------- 8-phase 256x256 GEMM (m201 template) + fused LSTM cell ----------------
// preact = A(8192x2048) * B(4096x2048)^T, cols gate-interleaved (4n+g).
// BK=64, 2 dbuf x 2 half x [128][64] per matrix = 128KB LDS. 8 waves; per-wave
// output = 4 quadrant strips 64x32 so phase (mh,nh) touches ONLY A-half mh /
// B-half nh -> half-tile-granular staging is race-free (target's last reader
// barrier'd before stage issues). vmcnt(4) once per K-tile (2 hts in flight).
// Swizzle: 16B-slot ^= row&7 (inverse-swz global source, swz ds_read).
#define SB  __builtin_amdgcn_sched_barrier(0)
#define BAR __builtin_amdgcn_s_barrier()
#define LGKM0 asm volatile("s_waitcnt lgkmcnt(0)" ::: "memory")

__global__ void __launch_bounds__(512, 2) gemm_lstm(
        const unsigned short* __restrict__ A,
        const unsigned short* __restrict__ Bw,
        const float* __restrict__ c0p,
        const float* __restrict__ bsum,
        float* __restrict__ outp) {
    // elems: A region [0,32768): d*16384 + h*8192 + row*64 + slot*8 ; B at +32768
    __shared__ __align__(16) unsigned short lds[65536];

    const int bid = blockIdx.x;                 // 512 blocks, %8==0 -> bijective XCD swizzle
    const int swz = ((bid & 7) << 6) | (bid >> 3);
    const int bm = swz & 31;                    // 32 M-blocks
    const int bn = swz >> 5;                    // 16 N-blocks
    const int t = threadIdx.x;
    const int lane = t & 63;
    const int wave = t >> 6;
    const int wm = wave >> 2;                   // 0-1: 64-row strip within each A-half
    const int wn = wave & 3;                    // 0-3: 32-col strip within each B-half

    f32x4 acc[2][2][4][2];
#pragma unroll
    for (int a = 0; a < 2; ++a)
#pragma unroll
        for (int b = 0; b < 2; ++b)
#pragma unroll
            for (int m = 0; m < 4; ++m)
#pragma unroll
                for (int n = 0; n < 2; ++n)
                    acc[a][b][m][n] = (f32x4){0.f, 0.f, 0.f, 0.f};

    // ---- staging geometry: half-tile = 128 rows x 64 k bf16 = 16KB = 1024 x 16B chunks.
    // thread t -> chunks t (rows 0-63) and t+512 (rows 64-127); slot = chunk&7,
    // global k-slot = slot ^ (row&7) (inverse swizzle; row&7 same for both chunks).
    const int srow = t >> 3;                    // 0..63
    const int sslot = (t & 7) ^ (srow & 7);
    const unsigned short* aSrc = A  + (size_t)(bm * 256 + srow) * KD + sslot * 8;
    const unsigned short* bSrc = Bw + (size_t)(bn * 256 + srow) * KD + sslot * 8;
    const int dstOff = wave * 512;              // wave-uniform; HW adds lane*16B

#define STAGE_A(D, H, KT) do { \
    const unsigned short* _s = aSrc + (size_t)(H) * 128 * KD + (size_t)(KT) * 64; \
    __builtin_amdgcn_global_load_lds((const gu32_t*)_s, (lu32_t*)&lds[(D)*16384 + (H)*8192 + dstOff], 16, 0, 0); \
    __builtin_amdgcn_global_load_lds((const gu32_t*)(_s + (size_t)64 * KD), (lu32_t*)&lds[(D)*16384 + (H)*8192 + dstOff + 4096], 16, 0, 0); \
  } while (0)
#define STAGE_B(D, H, KT) do { \
    const unsigned short* _s = bSrc + (size_t)(H) * 128 * KD + (size_t)(KT) * 64; \
    __builtin_amdgcn_global_load_lds((const gu32_t*)_s, (lu32_t*)&lds[32768 + (D)*16384 + (H)*8192 + dstOff], 16, 0, 0); \
    __builtin_amdgcn_global_load_lds((const gu32_t*)(_s + (size_t)64 * KD), (lu32_t*)&lds[32768 + (D)*16384 + (H)*8192 + dstOff + 4096], 16, 0, 0); \
  } while (0)

    // ---- ds-read geometry ----
    const int r15 = lane & 15;
    const int g4 = lane >> 4;
    const int x7 = r15 & 7;
    const int slotE0 = (g4 ^ x7) * 8;           // kk=0
    const int slotE1 = ((4 | g4) ^ x7) * 8;     // kk=1
    const int aRowOff = (wm * 64 + r15) * 64;
    const int bRowOff = 32768 + (wn * 32 + r15) * 64;

#define LDA(D, MH, M, SL) (*(const bf16x8*)&lds[(D)*16384 + (MH)*8192 + aRowOff + (M)*1024 + (SL)])
#define LDB(D, NH, N, SL) (*(const bf16x8*)&lds[(D)*16384 + (NH)*8192 + bRowOff + (N)*1024 + (SL)])

    bf16x8 af[2][4], bf[2][2][2];

#define MFMA_Q(MH, NH) do { \
    __builtin_amdgcn_s_setprio(1); \
    _Pragma("unroll") \
    for (int kk = 0; kk < 2; ++kk) \
      _Pragma("unroll") \
      for (int m = 0; m < 4; ++m) \
        _Pragma("unroll") \
        for (int n = 0; n < 2; ++n) \
          acc[MH][NH][m][n] = __builtin_amdgcn_mfma_f32_16x16x32_bf16(af[kk][m], bf[NH][kk][n], acc[MH][NH][m][n], 0, 0, 0); \
    __builtin_amdgcn_s_setprio(0); \
  } while (0)

    // ---- one K-tile = 4 quadrant phases ----
#define KTILE(D, T64) do { \
    const int dn_ = (D) ^ 1; \
    /* q0 (mh0,nh0): 8A + 4B reads */ \
    _Pragma("unroll") for (int m = 0; m < 4; ++m) af[0][m] = LDA(D, 0, m, slotE0); \
    _Pragma("unroll") for (int m = 0; m < 4; ++m) af[1][m] = LDA(D, 0, m, slotE1); \
    _Pragma("unroll") for (int n = 0; n < 2; ++n) bf[0][0][n] = LDB(D, 0, n, slotE0); \
    _Pragma("unroll") for (int n = 0; n < 2; ++n) bf[0][1][n] = LDB(D, 0, n, slotE1); \
    if ((T64) < 31) STAGE_A(dn_, 1, (T64) + 1); \
    SB; BAR; LGKM0; SB; \
    MFMA_Q(0, 0); \
    if ((T64) == 31) asm volatile("s_waitcnt vmcnt(0)" ::: "memory"); \
    SB; BAR; \
    /* q1 (mh0,nh1): 4B reads */ \
    _Pragma("unroll") for (int n = 0; n < 2; ++n) bf[1][0][n] = LDB(D, 1, n, slotE0); \
    _Pragma("unroll") for (int n = 0; n < 2; ++n) bf[1][1][n] = LDB(D, 1, n, slotE1); \
    if ((T64) < 31) STAGE_B(dn_, 1, (T64) + 1); \
    SB; BAR; LGKM0; SB; \
    MFMA_Q(0, 1); \
    SB; BAR; \
    /* q2 (mh1,nh0): 8A reads */ \
    _Pragma("unroll") for (int m = 0; m < 4; ++m) af[0][m] = LDA(D, 1, m, slotE0); \
    _Pragma("unroll") for (int m = 0; m < 4; ++m) af[1][m] = LDA(D, 1, m, slotE1); \
    if ((T64) < 30) STAGE_A(D, 0, (T64) + 2); \
    SB; BAR; LGKM0; SB; \
    MFMA_Q(1, 0); \
    SB; BAR; \
    /* q3 (mh1,nh1): 0 reads */ \
    if ((T64) < 30) STAGE_B(D, 0, (T64) + 2); \
    SB; BAR; SB; \
    MFMA_Q(1, 1); \
    if ((T64) < 31) asm volatile("s_waitcnt vmcnt(4)" ::: "memory"); \
    SB; BAR; \
  } while (0)

    // ---- prologue: K-tile 0 (4 hts) + K-tile 1 first 2 hts; vmcnt(4) -> tile 0 resident ----
    STAGE_A(0, 0, 0); STAGE_B(0, 0, 0); STAGE_A(0, 1, 0); STAGE_B(0, 1, 0);
    STAGE_A(1, 0, 1); STAGE_B(1, 0, 1);
    asm volatile("s_waitcnt vmcnt(4)" ::: "memory");
    SB; BAR; SB;

    for (int tp = 0; tp < 16; ++tp) {
        const int t0 = tp * 2;
        KTILE(0, t0);
        KTILE(1, t0 + 1);
    }

    // ---- fused epilogue: 4 chunks of 64 rows x 256 cols via swizzled fp32 LDS re-stage ----
    // acc row = mh*128 + wm*64 + m*16 + g4*4 + j ; col = nh*128 + wn*32 + n*16 + r15
    float* pre = (float*)&lds[0];               // 64KB = [64][256] f32
    const int lr = t >> 3;                      // 0..63
    const int cg = t & 7;                       // 32-col group
    const int rswz = (lr & 7) << 2;
#pragma unroll
    for (int c = 0; c < 4; ++c) {
        __syncthreads();
        if (wm == (c & 1)) {
            const int mh = c >> 1;
#pragma unroll
            for (int nh = 0; nh < 2; ++nh)
#pragma unroll
                for (int n = 0; n < 2; ++n) {
                    const int col = nh * 128 + wn * 32 + n * 16 + r15;
#pragma unroll
                    for (int m = 0; m < 4; ++m)
#pragma unroll
                        for (int j = 0; j < 4; ++j) {
                            const int rw = m * 16 + g4 * 4 + j;
                            pre[rw * 256 + (col ^ ((rw & 7) << 2))] = acc[mh][nh][m][n][j];
                        }
                }
        }
        __syncthreads();
        const int R = bm * 256 + c * 64 + lr;
        const int64_t eo = (int64_t)R * DH + bn * 64 + cg * 8;
        f32x4 cp0 = *(const f32x4*)&c0p[eo];
        f32x4 cp1 = *(const f32x4*)&c0p[eo + 4];
        float hbuf[8], cbuf[8];
#pragma unroll
        for (int g8 = 0; g8 < 8; ++g8) {
            const int colf = cg * 32 + g8 * 4;
            f32x4 pr = *(const f32x4*)&pre[lr * 256 + (colf ^ rswz)];
            f32x4 bs = *(const f32x4*)&bsum[bn * 256 + colf];
            float it = sigmoidf_(pr[0] + bs[0]);
            float ft = sigmoidf_(pr[1] + bs[1]);
            float gt = tanhf_(pr[2] + bs[2]);
            float ot = sigmoidf_(pr[3] + bs[3]);
            float cprev = (g8 < 4) ? cp0[g8 & 3] : cp1[g8 & 3];
            float ct = ft * cprev + it * gt;
            cbuf[g8] = ct;
            hbuf[g8] = ot * tanhf_(ct);
        }
        f32x4 h0v = {hbuf[0], hbuf[1], hbuf[2], hbuf[3]};
        f32x4 h1v = {hbuf[4], hbuf[5], hbuf[6], hbuf[7]};
        f32x4 c0v = {cbuf[0], cbuf[1], cbuf[2], cbuf[3]};
        f32x4 c1v = {cbuf[4], cbuf[5], cbuf[6], cbuf[7]};
        *(f32x4*)&outp[eo] = h0v;
        *(f32x4*)&outp[eo + 4] = h1v;
        *(f32x4*)&outp[(int64_t)BATCH * DH + eo] = c0v;
        *(f32x4*)&outp[(int64_t)BATCH * DH + eo + 4] = c1v;
    }
}

extern "C" void kernel_launch(void* const* d_in, const int* in_sizes, int n_in,
                              void* d_out, int out_size, void* d_ws, size_t ws_size,
                              hipStream_t stream) {
    const float* x   = (const float*)d_in[0];
    const float* h0  = (const float*)d_in[1];
    const float* c0  = (const float*)d_in[2];
    const float* Wii = (const float*)d_in[3];
    const float* bii = (const float*)d_in[4];
    const float* Wih = (const float*)d_in[5];
    const float* bih = (const float*)d_in[6];
    const float* Wfi = (const float*)d_in[7];
    const float* bfi = (const float*)d_in[8];
    const float* Wfh = (const float*)d_in[9];
    const float* bfh = (const float*)d_in[10];
    const float* Wgi = (const float*)d_in[11];
    const float* bgi = (const float*)d_in[12];
    const float* Wgh = (const float*)d_in[13];
    const float* bgh = (const float*)d_in[14];
    const float* Woi = (const float*)d_in[15];
    const float* boi = (const float*)d_in[16];
    const float* Woh = (const float*)d_in[17];
    const float* boh = (const float*)d_in[18];

    // ws layout: A bf16 32MB | B bf16 16MB | bsum 16KB
    unsigned short* A  = (unsigned short*)d_ws;
    unsigned short* Bw = A + (size_t)BATCH * KD;
    float* bsum = (float*)(Bw + (size_t)ND * KD);
    float* out = (float*)d_out;

    convert_all<<<12290, 256, 0, stream>>>(x, h0,
        Wii, Wih, Wfi, Wfh, Wgi, Wgh, Woi, Woh,
        bii, bih, bfi, bfh, bgi, bgh, boi, boh,
        A, Bw, bsum);
    gemm_lstm<<<512, 512, 0, stream>>>(A, Bw, c0, bsum, out);
}